// Round 8
// baseline (72.010 us; speedup 1.0000x reference)
//
#include <hip/hip_runtime.h>
#include <hip/hip_bf16.h>

#define NB 4
#define CCH 256
#define NN 4096
#define QT 128
#define KSPLIT 4
#define MRANGE (NN / KSPLIT)
#define MTILE 32
#define NTILES (MRANGE / MTILE)

// sqrt(log2(e)/16): fold softmax scale + exp2 conversion into x symmetrically
#define SQRTK 0.30028060f

typedef __attribute__((ext_vector_type(8))) short short8;
typedef __attribute__((ext_vector_type(16))) float f32x16;

__device__ inline ushort f2bf(float f) {
    uint u = __float_as_uint(f);
    uint r = (u + 0x7fffu + ((u >> 16) & 1u)) >> 16;
    return (ushort)r;
}

__device__ inline float dev_exp2(float x) {
#if __has_builtin(__builtin_amdgcn_exp2f)
    return __builtin_amdgcn_exp2f(x);
#else
    return exp2f(x);
#endif
}

__device__ inline void gl_lds16(const void* g, void* l) {
    __builtin_amdgcn_global_load_lds(
        (const __attribute__((address_space(1))) unsigned int*)g,
        (__attribute__((address_space(3))) unsigned int*)l, 16, 0, 0);
}

// ---------------- Kernel A: transpose inp [B][C][N] fp32 -> inpT [B][N][C] bf16
//                  + tail blocks (>=1024): W fp32 -> bf16 conversion
__global__ __launch_bounds__(256) void transp_k(const float* __restrict__ inp,
                                                ushort* __restrict__ inpT,
                                                const float* __restrict__ W,
                                                ushort* __restrict__ Wb) {
    if (blockIdx.x >= 1024) {            // 64 tail wgs: convert W (16384 float4)
        int i = (blockIdx.x - 1024) * 256 + threadIdx.x;
        float4 v = reinterpret_cast<const float4*>(W)[i];
        ushort4 r;
        r.x = f2bf(v.x); r.y = f2bf(v.y); r.z = f2bf(v.z); r.w = f2bf(v.w);
        reinterpret_cast<ushort4*>(Wb)[i] = r;
        return;
    }
    int wg = blockIdx.x;                 // 1024: b(2) | cblk(2) | nblk(6)
    int nblk = wg & 63, cblk = (wg >> 6) & 3, b = wg >> 8;
    __shared__ float tile[64 * 67];
    int t = threadIdx.x;
    const float* src = inp + ((size_t)(b * CCH + cblk * 64)) * NN + nblk * 64;
#pragma unroll
    for (int p = 0; p < 4; p++) {
        int ci = p * 256 + t;            // 0..1023
        int c = ci >> 4, n4 = ci & 15;
        float4 v = *reinterpret_cast<const float4*>(src + (size_t)c * NN + n4 * 4);
        float* d = &tile[c * 67 + n4 * 4];
        d[0] = v.x; d[1] = v.y; d[2] = v.z; d[3] = v.w;
    }
    __syncthreads();
    ushort* dst = inpT + ((size_t)(b * NN + nblk * 64)) * CCH + cblk * 64;
#pragma unroll
    for (int p = 0; p < 2; p++) {
        int u = p * 256 + t;             // 0..511
        int n = u >> 3, cc = u & 7;
        ushort tmp[8];
#pragma unroll
        for (int j = 0; j < 8; j++) tmp[j] = f2bf(tile[(cc * 8 + j) * 67 + n]);
        uint4 o;
        o.x = (uint)tmp[0] | ((uint)tmp[1] << 16);
        o.y = (uint)tmp[2] | ((uint)tmp[3] << 16);
        o.z = (uint)tmp[4] | ((uint)tmp[5] << 16);
        o.w = (uint)tmp[6] | ((uint)tmp[7] << 16);
        *reinterpret_cast<uint4*>(dst + (size_t)n * CCH + cc * 8) = o;
    }
}

// ---------------- Kernel B: xs[b][n][o] = bf16( (inpT[b][n][:] . Wb[o][:] + bias[o]) * SQRTK )
__global__ __launch_bounds__(256) void linear_k(const ushort* __restrict__ inpT,
                                                const ushort* __restrict__ Wb,
                                                const float* __restrict__ bias,
                                                ushort* __restrict__ xs) {
    int wg = blockIdx.x;                 // 256: b(2) | ntile(6)
    int b = wg >> 6, nt = wg & 63;
    int t = threadIdx.x, l = t & 63, w = t >> 6;
    int nbase = nt * 64 + (w & 1) * 32;
    int obase = (w >> 1) * 128;
    const ushort* arow = inpT + ((size_t)(b * NN + nbase + (l & 31))) * CCH + ((l >> 5) * 8);
    const ushort* wrow = Wb + ((size_t)(obase + (l & 31))) * CCH + ((l >> 5) * 8);
    f32x16 acc[4];
#pragma unroll
    for (int os = 0; os < 4; os++)
#pragma unroll
        for (int r = 0; r < 16; r++) acc[os][r] = 0.f;

#pragma unroll
    for (int ch = 0; ch < 16; ch++) {
        short8 a = *reinterpret_cast<const short8*>(arow + ch * 16);
#pragma unroll
        for (int os = 0; os < 4; os++) {
            short8 bb = *reinterpret_cast<const short8*>(wrow + (size_t)os * 32 * CCH + ch * 16);
            acc[os] = __builtin_amdgcn_mfma_f32_32x32x16_bf16(a, bb, acc[os], 0, 0, 0);
        }
    }
#pragma unroll
    for (int os = 0; os < 4; os++) {
        int oc = obase + os * 32 + (l & 31);
        float bv = bias[oc];
#pragma unroll
        for (int r = 0; r < 16; r++) {
            int row = (r & 3) + 8 * (r >> 2) + 4 * (l >> 5);
            float v = (acc[os][r] + bv) * SQRTK;
            xs[((size_t)(b * NN + nt * 64 + (w & 1) * 32 + row)) * CCH + oc] = f2bf(v);
        }
    }
}

// ---------------- Kernel C: flash attention with V=[fx,fy], no-max online softmax
// grid 512 = 2 independent 4-wave wgs per CU (R7 structure) + T3/T4 pipeline:
// 3-buffer LDS rotation, distance-2 prefetch, raw s_barrier with counted
// vmcnt(4) (never 0 mid-loop) so staged loads stay in flight across barriers.
// flow[] pre-staged to LDS -> compute phase has ZERO VMEM ops (keeps the
// vmcnt count exact and stops compiler drains). NO unroll on the tile loop
// (R6: full unroll + sched pins -> catastrophic scratch spills).
// S split into S0/S1: two 8-deep MFMA chains instead of one 16-deep.
__global__ __launch_bounds__(256) void attn_k(const ushort* __restrict__ xs,
                                              const float* __restrict__ flow,
                                              float* __restrict__ part) {
    int wg = blockIdx.x;                 // 512: b(2) | qt(5) | ks(2)
    int b = wg >> 7;
    int qt = (wg >> 2) & 31;
    int ks = wg & 3;
    int t = threadIdx.x, l = t & 63, w = t >> 6;   // w = 0..3
    const ushort* xb = xs + (size_t)b * NN * CCH;
    int qbase = qt * QT + w * 32;
    int mstart = ks * MRANGE;

    __shared__ ushort kt[3][MTILE * 256];   // 3 x 16KB K-tiles
    __shared__ float flds[2 * MRANGE];      // 8KB: fx slice | fy slice

    // stage flow slice (8KB): 4 waves x 2 chunks of 1KB. LDS dest is
    // wave-uniform base (HW adds lane*16); global src carries l*16.
#pragma unroll
    for (int p = 0; p < 2; p++) {
        int c = w * 2 + p;               // 0..7
        int half = c >> 2, quad = c & 3;
        const char* fsrc = (const char*)(flow + (size_t)b * 2 * NN + (size_t)half * NN
                                         + mstart + quad * 256) + l * 16;
        gl_lds16(fsrc, (char*)flds + c * 1024);
    }

    // Q fragments in registers: 32 q-rows x 256 c per wave
    short8 qf[16];
    const ushort* qrow = xb + ((size_t)(qbase + (l & 31))) * CCH + (l >> 5) * 8;
#pragma unroll
    for (int ch = 0; ch < 16; ch++)
        qf[ch] = *reinterpret_cast<const short8*>(qrow + ch * 16);

    float accS[16], accX[16], accY[16];
#pragma unroll
    for (int r = 0; r < 16; r++) { accS[r] = 0.f; accX[r] = 0.f; accY[r] = 0.f; }

    // staging one 32-row K-tile (16KB = 16 chunks of 1KB; 4 per wave);
    // source XOR-swizzled (16 slots) so linear-LDS global_load_lds yields
    // conflict-free swizzled ds_read_b128 later
    auto stage = [&](int buf, int tile) {
        int mb = mstart + tile * MTILE;
        const char* src = (const char*)(xb + (size_t)mb * CCH);
#pragma unroll
        for (int p = 0; p < 4; p++) {
            int chunk = w * 4 + p;
            int lin = chunk * 1024 + l * 16;
            int row = lin >> 9;
            int cb = lin & 511;
            int gsw = cb ^ ((row & 15) << 4);
            gl_lds16(src + (size_t)row * 512 + gsw, &kt[buf][chunk * 512]);
        }
    };

    stage(0, 0);
    stage(1, 1);
    // in flight per wave: 2 (flow) + 4 (t0) + 4 (t1)

    int cur = 0;
    for (int tile = 0; tile < NTILES; tile++) {
        // Ensure tile's stage (issued 2 iters ago) landed: outstanding is at
        // most stage(tile) 4 + stage(tile+1) 4 -> vmcnt(4) drains the oldest.
        // Last iter: only own 4 outstanding -> must drain fully.
        if (tile + 1 < NTILES) {
            asm volatile("s_waitcnt vmcnt(4)" ::: "memory");
        } else {
            asm volatile("s_waitcnt vmcnt(0)" ::: "memory");
        }
        __builtin_amdgcn_s_barrier();
        __builtin_amdgcn_sched_barrier(0);

        // prefetch distance 2: writes buf (cur+2)%3, read two iters from now.
        // Safe: every wave passed the barrier above, so compute(tile-1) reads
        // of this buffer are complete wg-wide.
        if (tile + 2 < NTILES) {
            int nbuf = cur + 2; if (nbuf >= 3) nbuf -= 3;
            stage(nbuf, tile + 2);
        }

        f32x16 S0, S1;
#pragma unroll
        for (int r = 0; r < 16; r++) { S0[r] = 0.f; S1[r] = 0.f; }
        const char* base = (const char*)&kt[cur][(l & 31) * 256];
        int swz = (l & 15) << 4;
        __builtin_amdgcn_s_setprio(1);
#pragma unroll
        for (int ch = 0; ch < 16; ch += 2) {
            int cb0 = (ch * 32 + ((l >> 5) * 16)) ^ swz;
            int cb1 = ((ch + 1) * 32 + ((l >> 5) * 16)) ^ swz;
            short8 bf0 = *reinterpret_cast<const short8*>(base + cb0);
            short8 bf1 = *reinterpret_cast<const short8*>(base + cb1);
            S0 = __builtin_amdgcn_mfma_f32_32x32x16_bf16(qf[ch], bf0, S0, 0, 0, 0);
            S1 = __builtin_amdgcn_mfma_f32_32x32x16_bf16(qf[ch + 1], bf1, S1, 0, 0, 0);
        }
        __builtin_amdgcn_s_setprio(0);

        int moff = tile * MTILE + (l & 31);
        float fx = flds[moff];
        float fy = flds[MRANGE + moff];
#pragma unroll
        for (int r = 0; r < 16; r++) {
            float e = dev_exp2(S0[r] + S1[r]);
            accS[r] += e;
            accX[r] += e * fx;
            accY[r] += e * fy;
        }
        cur = (cur == 2) ? 0 : cur + 1;
    }

    // reduce across the 32 columns (m-subsets); rows differ between lane halves
#pragma unroll
    for (int r = 0; r < 16; r++) {
        float s = accS[r], x = accX[r], y = accY[r];
#pragma unroll
        for (int off = 1; off < 32; off <<= 1) {
            s += __shfl_xor(s, off, 64);
            x += __shfl_xor(x, off, 64);
            y += __shfl_xor(y, off, 64);
        }
        if ((l & 31) == 0) {
            int row = (r & 3) + 8 * (r >> 2) + 4 * (l >> 5);
            int q = qt * QT + w * 32 + row;
            float* pb = part + ((size_t)(b * KSPLIT + ks)) * 3 * NN;
            pb[q] = s;
            pb[NN + q] = x;
            pb[2 * NN + q] = y;
        }
    }
}

// ---------------- Kernel D: combine k-split partials, divide, write output
__global__ void finalize_k(const float* __restrict__ part, float* __restrict__ out) {
    int i = blockIdx.x * 256 + threadIdx.x;  // 16384
    int b = i >> 12, n = i & 4095;
    float s = 0.f, x = 0.f, y = 0.f;
#pragma unroll
    for (int ks = 0; ks < KSPLIT; ks++) {
        const float* p = part + ((size_t)(b * KSPLIT + ks)) * 3 * NN;
        s += p[n];
        x += p[NN + n];
        y += p[2 * NN + n];
    }
    out[(size_t)b * 2 * NN + n] = x / s;
    out[(size_t)b * 2 * NN + NN + n] = y / s;
}

extern "C" void kernel_launch(void* const* d_in, const int* in_sizes, int n_in,
                              void* d_out, int out_size, void* d_ws, size_t ws_size,
                              hipStream_t stream) {
    const float* inp  = (const float*)d_in[0];
    // d_in[1] = inter_mask: unused by the reference
    const float* flow = (const float*)d_in[2];
    const float* W    = (const float*)d_in[3];
    const float* bias = (const float*)d_in[4];
    float* out = (float*)d_out;

    char* ws = (char*)d_ws;
    ushort* xs   = (ushort*)(ws);                  // 8 MB  x_scaled bf16 [B][N][C]
    ushort* inpT = (ushort*)(ws + 8388608);        // 8 MB  inp^T bf16   [B][N][C]
    ushort* Wb   = (ushort*)(ws + 16777216);       // 128KB W bf16       [C][C]
    // part overlaps inpT's region: inpT is dead after linear_k, part is
    // written by attn_k afterwards; deterministic each replay.
    float*  part = (float*)(ws + 8388608);         // 768KB partials [B][KS][3][N]

    transp_k<<<1088, 256, 0, stream>>>(inp, inpT, W, Wb);
    linear_k<<<256, 256, 0, stream>>>(inpT, Wb, bias, xs);
    attn_k<<<512, 256, 0, stream>>>(xs, flow, part);
    finalize_k<<<64, 256, 0, stream>>>(part, out);
}

// Round 9
// 65.795 us; speedup vs baseline: 1.0945x; 1.0945x over previous
//
#include <hip/hip_runtime.h>
#include <hip/hip_bf16.h>

#define NB 4
#define CCH 256
#define NN 4096
#define QT 128
#define KSPLIT 4
#define MRANGE (NN / KSPLIT)
#define MTILE 64
#define NTILES (MRANGE / MTILE)
#define VPAD 8

// sqrt(log2(e)/16): fold softmax scale + exp2 conversion into x symmetrically
#define SQRTK 0.30028060f

typedef __attribute__((ext_vector_type(8))) short short8;
typedef __attribute__((ext_vector_type(16))) float f32x16;
typedef __attribute__((ext_vector_type(4))) int i32x4;

__device__ inline ushort f2bf(float f) {
    uint u = __float_as_uint(f);
    uint r = (u + 0x7fffu + ((u >> 16) & 1u)) >> 16;
    return (ushort)r;
}

__device__ inline float dev_exp2(float x) {
#if __has_builtin(__builtin_amdgcn_exp2f)
    return __builtin_amdgcn_exp2f(x);
#else
    return exp2f(x);
#endif
}

__device__ inline void gl_lds16(const void* g, void* l) {
    __builtin_amdgcn_global_load_lds(
        (const __attribute__((address_space(1))) unsigned int*)g,
        (__attribute__((address_space(3))) unsigned int*)l, 16, 0, 0);
}

// ---------------- Kernel A: transpose inp [B][C][N] fp32 -> inpT [B][N][C] bf16
//                  + tail blocks (>=1024): W fp32 -> bf16 conversion
__global__ __launch_bounds__(256) void transp_k(const float* __restrict__ inp,
                                                ushort* __restrict__ inpT,
                                                const float* __restrict__ W,
                                                ushort* __restrict__ Wb) {
    if (blockIdx.x >= 1024) {            // 64 tail wgs: convert W (16384 float4)
        int i = (blockIdx.x - 1024) * 256 + threadIdx.x;
        float4 v = reinterpret_cast<const float4*>(W)[i];
        ushort4 r;
        r.x = f2bf(v.x); r.y = f2bf(v.y); r.z = f2bf(v.z); r.w = f2bf(v.w);
        reinterpret_cast<ushort4*>(Wb)[i] = r;
        return;
    }
    int wg = blockIdx.x;                 // 1024: b(2) | cblk(2) | nblk(6)
    int nblk = wg & 63, cblk = (wg >> 6) & 3, b = wg >> 8;
    __shared__ float tile[64 * 67];
    int t = threadIdx.x;
    const float* src = inp + ((size_t)(b * CCH + cblk * 64)) * NN + nblk * 64;
#pragma unroll
    for (int p = 0; p < 4; p++) {
        int ci = p * 256 + t;            // 0..1023
        int c = ci >> 4, n4 = ci & 15;
        float4 v = *reinterpret_cast<const float4*>(src + (size_t)c * NN + n4 * 4);
        float* d = &tile[c * 67 + n4 * 4];
        d[0] = v.x; d[1] = v.y; d[2] = v.z; d[3] = v.w;
    }
    __syncthreads();
    ushort* dst = inpT + ((size_t)(b * NN + nblk * 64)) * CCH + cblk * 64;
#pragma unroll
    for (int p = 0; p < 2; p++) {
        int u = p * 256 + t;             // 0..511
        int n = u >> 3, cc = u & 7;
        ushort tmp[8];
#pragma unroll
        for (int j = 0; j < 8; j++) tmp[j] = f2bf(tile[(cc * 8 + j) * 67 + n]);
        uint4 o;
        o.x = (uint)tmp[0] | ((uint)tmp[1] << 16);
        o.y = (uint)tmp[2] | ((uint)tmp[3] << 16);
        o.z = (uint)tmp[4] | ((uint)tmp[5] << 16);
        o.w = (uint)tmp[6] | ((uint)tmp[7] << 16);
        *reinterpret_cast<uint4*>(dst + (size_t)n * CCH + cc * 8) = o;
    }
}

// ---------------- Kernel B: xs[b][n][o] = bf16( (inpT[b][n][:] . Wb[o][:] + bias[o]) * SQRTK )
__global__ __launch_bounds__(256) void linear_k(const ushort* __restrict__ inpT,
                                                const ushort* __restrict__ Wb,
                                                const float* __restrict__ bias,
                                                ushort* __restrict__ xs) {
    int wg = blockIdx.x;                 // 256: b(2) | ntile(6)
    int b = wg >> 6, nt = wg & 63;
    int t = threadIdx.x, l = t & 63, w = t >> 6;
    int nbase = nt * 64 + (w & 1) * 32;
    int obase = (w >> 1) * 128;
    const ushort* arow = inpT + ((size_t)(b * NN + nbase + (l & 31))) * CCH + ((l >> 5) * 8);
    const ushort* wrow = Wb + ((size_t)(obase + (l & 31))) * CCH + ((l >> 5) * 8);
    f32x16 acc[4];
#pragma unroll
    for (int os = 0; os < 4; os++)
#pragma unroll
        for (int r = 0; r < 16; r++) acc[os][r] = 0.f;

#pragma unroll
    for (int ch = 0; ch < 16; ch++) {
        short8 a = *reinterpret_cast<const short8*>(arow + ch * 16);
#pragma unroll
        for (int os = 0; os < 4; os++) {
            short8 bb = *reinterpret_cast<const short8*>(wrow + (size_t)os * 32 * CCH + ch * 16);
            acc[os] = __builtin_amdgcn_mfma_f32_32x32x16_bf16(a, bb, acc[os], 0, 0, 0);
        }
    }
#pragma unroll
    for (int os = 0; os < 4; os++) {
        int oc = obase + os * 32 + (l & 31);
        float bv = bias[oc];
#pragma unroll
        for (int r = 0; r < 16; r++) {
            int row = (r & 3) + 8 * (r >> 2) + 4 * (l >> 5);
            float v = (acc[os][r] + bv) * SQRTK;
            xs[((size_t)(b * NN + nt * 64 + (w & 1) * 32 + row)) * CCH + oc] = f2bf(v);
        }
    }
}

// ---------------- Kernel C: flash attention, PV + softmax-denominator via MFMA
// Swapped QK^T: S^T = mfma(K, Q) puts q on lanes, m in regs. P(bf16) then
// feeds PV directly: out[q][{X,Y,S}] = sum_m P^T[m][q] * V'[m][c] with
// V' = [fx, fy, 1, 0...] (the 1-column computes the softmax denominator).
// The A-frag k-mapping (k split across lane halves) is absorbed by storing
// V' rows PRE-PERMUTED in LDS (swap bits 2<->3 of m&15) so e-words pack in
// plain reg order: 8 cvt_pk, no permlane/shuffle. R7 shell (dbuf +
// __syncthreads, no launch-bound squeeze, no tile-loop unroll).
__global__ __launch_bounds__(256) void attn_k(const ushort* __restrict__ xs,
                                              const float* __restrict__ flow,
                                              float* __restrict__ part) {
    int wg = blockIdx.x;                 // 512: b(2) | qt(5) | ks(2)
    int b = wg >> 7;
    int qt = (wg >> 2) & 31;
    int ks = wg & 3;
    int t = threadIdx.x, l = t & 63, w = t >> 6;   // w = 0..3
    const ushort* xb = xs + (size_t)b * NN * CCH;
    int qbase = qt * QT + w * 32;
    int mstart = ks * MRANGE;

    __shared__ ushort kt[2][MTILE * 256];        // 2 x 32KB K-tiles
    __shared__ ushort vlds[4][MRANGE + VPAD];    // perm-ordered V': fx|fy|1|0

    // build V' (one-time): thread t handles m = t*4..t*4+3 of this wg's slice
    {
        int m0 = t * 4;
        float4 fx4 = *reinterpret_cast<const float4*>(flow + (size_t)b * 2 * NN + mstart + m0);
        float4 fy4 = *reinterpret_cast<const float4*>(flow + (size_t)b * 2 * NN + NN + mstart + m0);
        float fxv[4] = {fx4.x, fx4.y, fx4.z, fx4.w};
        float fyv[4] = {fy4.x, fy4.y, fy4.z, fy4.w};
#pragma unroll
        for (int i = 0; i < 4; i++) {
            int m = m0 + i, ml = m & 15;
            int pos = (m & ~15) | (ml & 3) | ((ml & 4) << 1) | ((ml & 8) >> 1);
            vlds[0][pos] = f2bf(fxv[i]);
            vlds[1][pos] = f2bf(fyv[i]);
            vlds[2][pos] = 0x3F80;       // bf16 1.0
            vlds[3][pos] = 0;
        }
    }

    // Q fragments in registers: 32 q-rows x 256 c per wave
    short8 qf[16];
    const ushort* qrow = xb + ((size_t)(qbase + (l & 31))) * CCH + (l >> 5) * 8;
#pragma unroll
    for (int ch = 0; ch < 16; ch++)
        qf[ch] = *reinterpret_cast<const short8*>(qrow + ch * 16);

    f32x16 pv;                           // persistent: cols {X,Y,S,0...} x 32 q
#pragma unroll
    for (int r = 0; r < 16; r++) pv[r] = 0.f;

    // staging: 32 chunks of 1KB across 4 waves; source XOR-swizzled (16 slots)
    auto stage = [&](int buf, int tile) {
        int mb = mstart + tile * MTILE;
        const char* src = (const char*)(xb + (size_t)mb * CCH);
#pragma unroll
        for (int p = 0; p < 8; p++) {
            int chunk = w * 8 + p;
            int lin = chunk * 1024 + l * 16;
            int row = lin >> 9;
            int cb = lin & 511;
            int gsw = cb ^ ((row & 15) << 4);
            gl_lds16(src + (size_t)row * 512 + gsw, &kt[buf][chunk * 512]);
        }
    };

    int c_sel = (l & 31) < 3 ? (l & 31) : 3;
    stage(0, 0);
    __syncthreads();
    int cur = 0;
    for (int tile = 0; tile < NTILES; tile++) {
        if (tile + 1 < NTILES) stage(cur ^ 1, tile + 1);
#pragma unroll
        for (int ms = 0; ms < 2; ms++) {
            f32x16 S;
#pragma unroll
            for (int r = 0; r < 16; r++) S[r] = 0.f;
            const char* base = (const char*)&kt[cur][(ms * 32 + (l & 31)) * 256];
            int swz = (l & 15) << 4;
#pragma unroll
            for (int ch = 0; ch < 16; ch++) {
                int cbyte = (ch * 32 + ((l >> 5) * 16)) ^ swz;
                short8 kf = *reinterpret_cast<const short8*>(base + cbyte);
                // swapped: A=K (rows=m), B=Q (cols=q)
                S = __builtin_amdgcn_mfma_f32_32x32x16_bf16(kf, qf[ch], S, 0, 0, 0);
            }
            // P = exp2(S), packed to bf16 in reg order (V' is pre-permuted)
#pragma unroll
            for (int r = 0; r < 16; r++) S[r] = dev_exp2(S[r]);
            uint wd[8];
#pragma unroll
            for (int p = 0; p < 8; p++) {
                float lo = S[2 * p], hi = S[2 * p + 1];
                asm("v_cvt_pk_bf16_f32 %0, %1, %2" : "=v"(wd[p]) : "v"(lo), "v"(hi));
            }
            i32x4 lo4 = {(int)wd[0], (int)wd[1], (int)wd[2], (int)wd[3]};
            i32x4 hi4 = {(int)wd[4], (int)wd[5], (int)wd[6], (int)wd[7]};
            short8 pa0 = __builtin_bit_cast(short8, lo4);
            short8 pa1 = __builtin_bit_cast(short8, hi4);
            int mloc = tile * MTILE + ms * 32;
            const ushort* vb = &vlds[c_sel][mloc + (l >> 5) * 8];
            short8 v0 = *reinterpret_cast<const short8*>(vb);
            short8 v1 = *reinterpret_cast<const short8*>(vb + 16);
            pv = __builtin_amdgcn_mfma_f32_32x32x16_bf16(pa0, v0, pv, 0, 0, 0);
            pv = __builtin_amdgcn_mfma_f32_32x32x16_bf16(pa1, v1, pv, 0, 0, 0);
        }
        __syncthreads();
        cur ^= 1;
    }

    // epilogue: lane col 0 holds X, col 1 holds Y, col 2 holds S (16 q each)
    int c = l & 31;
    if (c < 3) {
        float* pb = part + ((size_t)(b * KSPLIT + ks)) * 3 * NN;
        int off = ((c + 1) % 3) * NN;    // c2->S@0, c0->X@NN, c1->Y@2NN
#pragma unroll
        for (int r = 0; r < 16; r++) {
            int row = (r & 3) + 8 * (r >> 2) + 4 * (l >> 5);
            pb[off + qbase + row] = pv[r];
        }
    }
}

// ---------------- Kernel D: combine k-split partials, divide, write output
__global__ void finalize_k(const float* __restrict__ part, float* __restrict__ out) {
    int i = blockIdx.x * 256 + threadIdx.x;  // 16384
    int b = i >> 12, n = i & 4095;
    float s = 0.f, x = 0.f, y = 0.f;
#pragma unroll
    for (int ks = 0; ks < KSPLIT; ks++) {
        const float* p = part + ((size_t)(b * KSPLIT + ks)) * 3 * NN;
        s += p[n];
        x += p[NN + n];
        y += p[2 * NN + n];
    }
    out[(size_t)b * 2 * NN + n] = x / s;
    out[(size_t)b * 2 * NN + NN + n] = y / s;
}

extern "C" void kernel_launch(void* const* d_in, const int* in_sizes, int n_in,
                              void* d_out, int out_size, void* d_ws, size_t ws_size,
                              hipStream_t stream) {
    const float* inp  = (const float*)d_in[0];
    // d_in[1] = inter_mask: unused by the reference
    const float* flow = (const float*)d_in[2];
    const float* W    = (const float*)d_in[3];
    const float* bias = (const float*)d_in[4];
    float* out = (float*)d_out;

    char* ws = (char*)d_ws;
    ushort* xs   = (ushort*)(ws);                  // 8 MB  x_scaled bf16 [B][N][C]
    ushort* inpT = (ushort*)(ws + 8388608);        // 8 MB  inp^T bf16   [B][N][C]
    ushort* Wb   = (ushort*)(ws + 16777216);       // 128KB W bf16       [C][C]
    // part overlaps inpT's region: inpT is dead after linear_k, part is
    // written by attn_k afterwards; deterministic each replay.
    float*  part = (float*)(ws + 8388608);         // 768KB partials [B][KS][3][N]

    transp_k<<<1088, 256, 0, stream>>>(inp, inpT, W, Wb);
    linear_k<<<256, 256, 0, stream>>>(inpT, Wb, bias, xs);
    attn_k<<<512, 256, 0, stream>>>(xs, flow, part);
    finalize_k<<<64, 256, 0, stream>>>(part, out);
}